// Round 1
// baseline (14229.196 us; speedup 1.0000x reference)
//
#include <hip/hip_runtime.h>
#include <math.h>

// Problem constants
#define BB   64
#define HENC 512
#define EE   512
#define HH   1024
#define VV   32000
#define TT   64
#define G3   3072   // 3*H
#define SOS_TOK 1
#define EOS_TOK 2
#define KSEG 128

// Workspace layout (float offsets)
#define OFF_FLATT 0u          // 1024*64
#define OFF_XT    65536u      // 512*64
#define OFF_HT    98304u      // 1024*64  (hT[g][b])
#define OFF_GC    163840u     // 64*3072  (gc[b][n], includes b_ih + context proj)
#define OFF_P     360448u     // 12*64*3072 partials
#define OFF_PH    2719744u    // 8*64*1024 h0 partials
#define OFF_PMAX  3244032u    // 250*64 float
#define OFF_PIDX  3260032u    // 250*64 int
#define OFF_FIN   3276032u    // 2*64 int (double-buffered by t parity)

// ---------------------------------------------------------------------------
// Setup: flatT[j][b] = concat(enc[0][b], enc[1][b]) transposed; xT for t=0 (SOS);
// finished[0][b]=0
__global__ __launch_bounds__(256) void k_setup(const float* __restrict__ enc,
                                               const float* __restrict__ emb,
                                               float* __restrict__ flatT,
                                               float* __restrict__ xT,
                                               int* __restrict__ fin0) {
  int idx = blockIdx.x * 256 + threadIdx.x;   // 65536
  int j = idx >> 6, b = idx & 63;
  float v = (j < 512) ? enc[b * 512 + j] : enc[32768 + b * 512 + (j - 512)];
  flatT[j * 64 + b] = v;
  if (j < 512) xT[j * 64 + b] = emb[SOS_TOK * EE + j];
  if (idx < 64) fin0[idx] = 0;
}

// ---------------------------------------------------------------------------
// Generic skinny GEMM partial: C_part[by][b][n] = sum_{k in seg} AT[k][b] * W[n][wofs+k]
// AT is [K][64]; block tile: 64 n-cols x full 64 batch; 4 waves, wave w owns b=16w..16w+15.
__global__ __launch_bounds__(256) void k_gemm(const float* __restrict__ AT,
                                              const float* __restrict__ W,
                                              int ldw, int wofs,
                                              float* __restrict__ C, int N) {
  __shared__ float Ws[KSEG][65];
  int tid = threadIdx.x;
  int n0 = blockIdx.x * 64;
  int k0 = blockIdx.y * KSEG;

  // Stage W tile transposed: 64 rows x 128 k
  #pragma unroll
  for (int r = 0; r < 8; ++r) {
    int f4 = tid + 256 * r;
    int n = f4 >> 5, kq = f4 & 31;
    float4 w4 = *(const float4*)&W[(size_t)(n0 + n) * ldw + wofs + k0 + 4 * kq];
    Ws[4 * kq + 0][n] = w4.x;
    Ws[4 * kq + 1][n] = w4.y;
    Ws[4 * kq + 2][n] = w4.z;
    Ws[4 * kq + 3][n] = w4.w;
  }
  __syncthreads();

  int wv = __builtin_amdgcn_readfirstlane(tid >> 6);
  int lane = tid & 63;
  int mb = wv * 16;

  float acc[16];
  #pragma unroll
  for (int i = 0; i < 16; ++i) acc[i] = 0.f;

  #pragma unroll 4
  for (int kk = 0; kk < KSEG; ++kk) {
    float w = Ws[kk][lane];
    const float* a = &AT[(size_t)(k0 + kk) * 64 + mb];  // wave-uniform address
    float av[16];
    *(float4*)&av[0]  = *(const float4*)(a + 0);
    *(float4*)&av[4]  = *(const float4*)(a + 4);
    *(float4*)&av[8]  = *(const float4*)(a + 8);
    *(float4*)&av[12] = *(const float4*)(a + 12);
    #pragma unroll
    for (int i = 0; i < 16; ++i) acc[i] += av[i] * w;
  }

  float* dst = C + ((size_t)blockIdx.y * 64 + mb) * N + n0 + lane;
  #pragma unroll
  for (int i = 0; i < 16; ++i) dst[(size_t)i * N] = acc[i];
}

// ---------------------------------------------------------------------------
// gc[b][n] = sum_p Pgc[p][b][n] + b_ih[n]
__global__ __launch_bounds__(256) void k_reduce_gc(const float* __restrict__ P,
                                                   const float* __restrict__ b_ih,
                                                   float* __restrict__ gc) {
  int idx = blockIdx.x * 256 + threadIdx.x;  // 196608
  int n = idx % G3;
  float s = b_ih[n];
  #pragma unroll
  for (int p = 0; p < 8; ++p) s += P[(size_t)p * (64 * G3) + idx];
  gc[idx] = s;
}

// hT[g][b] = sum_p Ph[p][b][g] + Wh_b[g]
__global__ __launch_bounds__(256) void k_reduce_h0(const float* __restrict__ Ph,
                                                   const float* __restrict__ Wh_b,
                                                   float* __restrict__ hT) {
  int idx = blockIdx.x * 256 + threadIdx.x;  // 65536
  int b = idx >> 10, g = idx & 1023;
  float s = Wh_b[g];
  #pragma unroll
  for (int p = 0; p < 8; ++p) s += Ph[(size_t)p * 65536 + idx];
  hT[g * 64 + b] = s;
}

// ---------------------------------------------------------------------------
// GRU gate combine; P[0..3]=gi parts (x@Wih_x), P[4..11]=gh parts (h@Whh).
// Writes new h in transposed layout hT[g][b] (in place, no cross-thread deps).
__global__ __launch_bounds__(256) void k_combine(const float* __restrict__ P,
                                                 const float* __restrict__ gc,
                                                 const float* __restrict__ b_hh,
                                                 float* __restrict__ hT) {
  int b = blockIdx.x;
  #pragma unroll
  for (int r = 0; r < 4; ++r) {
    int g = threadIdx.x + 256 * r;
    float ir = gc[b * G3 + g];
    float iz = gc[b * G3 + 1024 + g];
    float in_ = gc[b * G3 + 2048 + g];
    float hr = b_hh[g], hz = b_hh[1024 + g], hn = b_hh[2048 + g];
    #pragma unroll
    for (int p = 0; p < 4; ++p) {
      const float* row = P + ((size_t)p * 64 + b) * G3;
      ir += row[g]; iz += row[1024 + g]; in_ += row[2048 + g];
    }
    #pragma unroll
    for (int p = 4; p < 12; ++p) {
      const float* row = P + ((size_t)p * 64 + b) * G3;
      hr += row[g]; hz += row[1024 + g]; hn += row[2048 + g];
    }
    float rr = 1.f / (1.f + expf(-(ir + hr)));
    float zz = 1.f / (1.f + expf(-(iz + hz)));
    float nn = tanhf(in_ + rr * hn);
    float hold = hT[g * 64 + b];
    hT[g * 64 + b] = (1.f - zz) * nn + zz * hold;
  }
}

// ---------------------------------------------------------------------------
// Logits GEMM (64 x 32000, K=1024) with fused per-block argmax partials.
// 250 blocks of 128 n-cols. Wave w owns b=16w..16w+15 (scalar/uniform A loads),
// lane owns 2 n-cols. Two-level accumulation for fp32 accuracy.
__global__ __launch_bounds__(256) void k_logits(const float* __restrict__ hT,
                                                const float* __restrict__ Wo,
                                                const float* __restrict__ bo,
                                                float* __restrict__ pmax,
                                                int* __restrict__ pidx) {
  __shared__ float Ws[32][130];
  int tid = threadIdx.x;
  int n0 = blockIdx.x * 128;
  int vrow = n0 + (tid >> 1);
  int ks = (tid & 1) * 16;
  int nloc = tid >> 1;
  const float* gsrc = Wo + (size_t)vrow * 1024 + ks;

  float4 pre[4];
  #pragma unroll
  for (int q = 0; q < 4; ++q) pre[q] = *(const float4*)(gsrc + 4 * q);

  int wv = __builtin_amdgcn_readfirstlane(tid >> 6);
  int lane = tid & 63;
  int mb = wv * 16;

  float acc0[16], acc1[16];
  #pragma unroll
  for (int i = 0; i < 16; ++i) { acc0[i] = 0.f; acc1[i] = 0.f; }

  for (int kt = 0; kt < 32; ++kt) {
    __syncthreads();
    #pragma unroll
    for (int q = 0; q < 4; ++q) {
      Ws[ks + 4 * q + 0][nloc] = pre[q].x;
      Ws[ks + 4 * q + 1][nloc] = pre[q].y;
      Ws[ks + 4 * q + 2][nloc] = pre[q].z;
      Ws[ks + 4 * q + 3][nloc] = pre[q].w;
    }
    __syncthreads();
    if (kt < 31) {
      const float* g2 = gsrc + (kt + 1) * 32;
      #pragma unroll
      for (int q = 0; q < 4; ++q) pre[q] = *(const float4*)(g2 + 4 * q);
    }
    int k0 = kt * 32;
    float t0[16], t1[16];
    #pragma unroll
    for (int i = 0; i < 16; ++i) { t0[i] = 0.f; t1[i] = 0.f; }
    #pragma unroll 8
    for (int kk = 0; kk < 32; ++kk) {
      float2 w2 = *(const float2*)&Ws[kk][2 * lane];
      const float* a = &hT[(size_t)(k0 + kk) * 64 + mb];  // wave-uniform
      float av[16];
      *(float4*)&av[0]  = *(const float4*)(a + 0);
      *(float4*)&av[4]  = *(const float4*)(a + 4);
      *(float4*)&av[8]  = *(const float4*)(a + 8);
      *(float4*)&av[12] = *(const float4*)(a + 12);
      #pragma unroll
      for (int i = 0; i < 16; ++i) { t0[i] += av[i] * w2.x; t1[i] += av[i] * w2.y; }
    }
    #pragma unroll
    for (int i = 0; i < 16; ++i) { acc0[i] += t0[i]; acc1[i] += t1[i]; }
  }

  // Epilogue: bias + per-block argmax (tie -> lowest index)
  float b0 = bo[n0 + 2 * lane];
  float b1 = bo[n0 + 2 * lane + 1];
  #pragma unroll
  for (int mi = 0; mi < 16; ++mi) {
    float v0 = acc0[mi] + b0;
    float v1 = acc1[mi] + b1;
    float val; int idx;
    if (v1 > v0) { val = v1; idx = n0 + 2 * lane + 1; }
    else         { val = v0; idx = n0 + 2 * lane; }
    #pragma unroll
    for (int s = 1; s < 64; s <<= 1) {
      float ov = __shfl_xor(val, s, 64);
      int   oi = __shfl_xor(idx, s, 64);
      if (ov > val || (ov == val && oi < idx)) { val = ov; idx = oi; }
    }
    if (lane == 0) {
      pmax[blockIdx.x * 64 + mb + mi] = val;
      pidx[blockIdx.x * 64 + mb + mi] = idx;
    }
  }
}

// ---------------------------------------------------------------------------
// Final argmax over 250 block-partials (redundantly in every block, deterministic),
// token/finished update (block 0 writes), and xT build for next step (all blocks).
__global__ __launch_bounds__(256) void k_argmax(const float* __restrict__ pmax,
                                                const int* __restrict__ pidx,
                                                const float* __restrict__ emb,
                                                const int* __restrict__ fin_old,
                                                int* __restrict__ fin_new,
                                                float* __restrict__ xT,
                                                float* __restrict__ tok_out, int t) {
  __shared__ float sv[4][64];
  __shared__ int   si[4][64];
  __shared__ int   sinp[64];
  __shared__ int   stok[64];
  __shared__ int   sfin[64];
  int tid = threadIdx.x, b = tid & 63, c = tid >> 6;
  float val = -3.402823466e38f;
  int idx = 0x7fffffff;
  for (int p = c; p < 250; p += 4) {
    float v = pmax[p * 64 + b];
    int i = pidx[p * 64 + b];
    if (v > val || (v == val && i < idx)) { val = v; idx = i; }
  }
  sv[c][b] = val; si[c][b] = idx;
  __syncthreads();
  if (c == 0) {
    #pragma unroll
    for (int q = 1; q < 4; ++q) {
      float v = sv[q][b]; int i = si[q][b];
      if (v > val || (v == val && i < idx)) { val = v; idx = i; }
    }
    int tok = idx;
    int f = fin_old[b] | (tok == EOS_TOK ? 1 : 0);
    stok[b] = tok;
    sfin[b] = f;
    sinp[b] = f ? EOS_TOK : tok;
  }
  __syncthreads();
  int inp = sinp[b];
  int k = blockIdx.x * 4 + c;   // 128 blocks * 4 = 512 = E
  xT[k * 64 + b] = emb[(size_t)inp * EE + k];
  if (blockIdx.x == 0 && c == 0) {
    tok_out[b * TT + t] = (float)stok[b];
    fin_new[b] = sfin[b];
  }
}

// ---------------------------------------------------------------------------
// Final hidden output: d_out[4096 + b*1024 + g] = hT[g][b]
__global__ __launch_bounds__(256) void k_hout(const float* __restrict__ hT,
                                              float* __restrict__ outH) {
  int idx = blockIdx.x * 256 + threadIdx.x;  // 65536
  int b = idx >> 10, g = idx & 1023;
  outH[idx] = hT[g * 64 + b];
}

// ---------------------------------------------------------------------------
extern "C" void kernel_launch(void* const* d_in, const int* in_sizes, int n_in,
                              void* d_out, int out_size, void* d_ws, size_t ws_size,
                              hipStream_t stream) {
  const float* enc   = (const float*)d_in[0];
  const float* emb   = (const float*)d_in[1];
  const float* Wh_w  = (const float*)d_in[2];
  const float* Wh_b  = (const float*)d_in[3];
  const float* W_ih  = (const float*)d_in[4];
  const float* W_hh  = (const float*)d_in[5];
  const float* b_ih  = (const float*)d_in[6];
  const float* b_hh  = (const float*)d_in[7];
  const float* out_w = (const float*)d_in[8];
  const float* out_b = (const float*)d_in[9];

  float* ws    = (float*)d_ws;
  float* flatT = ws + OFF_FLATT;
  float* xT    = ws + OFF_XT;
  float* hT    = ws + OFF_HT;
  float* gc    = ws + OFF_GC;
  float* P     = ws + OFF_P;
  float* Ph    = ws + OFF_PH;
  float* pmax  = ws + OFF_PMAX;
  int*   pidx  = (int*)(ws + OFF_PIDX);
  int*   fin   = (int*)(ws + OFF_FIN);

  float* outTok = (float*)d_out;
  float* outH   = (float*)d_out + BB * TT;

  // Setup
  k_setup<<<256, 256, 0, stream>>>(enc, emb, flatT, xT, fin);
  // gc partials: context @ W_ih[:,512:1536]^T  -> P[0..7]
  k_gemm<<<dim3(48, 8), 256, 0, stream>>>(flatT, W_ih, 1536, 512, P, G3);
  k_reduce_gc<<<768, 256, 0, stream>>>(P, b_ih, gc);
  // h0 partials: flat @ Wh_w^T -> Ph, reduce+transpose -> hT
  k_gemm<<<dim3(16, 8), 256, 0, stream>>>(flatT, Wh_w, 1024, 0, Ph, HH);
  k_reduce_h0<<<256, 256, 0, stream>>>(Ph, Wh_b, hT);

  for (int t = 0; t < TT; ++t) {
    // gi partials (x @ W_ih[:, :512]^T) -> P[0..3]
    k_gemm<<<dim3(48, 4), 256, 0, stream>>>(xT, W_ih, 1536, 0, P, G3);
    // gh partials (h @ W_hh^T) -> P[4..11]
    k_gemm<<<dim3(48, 8), 256, 0, stream>>>(hT, W_hh, 1024, 0, P + (size_t)4 * 64 * G3, G3);
    // GRU combine -> new hT
    k_combine<<<64, 256, 0, stream>>>(P, gc, b_hh, hT);
    // logits + per-block argmax partials
    k_logits<<<250, 256, 0, stream>>>(hT, out_w, out_b, pmax, pidx);
    // final argmax, token write, finished update, next-step embedding gather
    k_argmax<<<128, 256, 0, stream>>>(pmax, pidx, emb,
                                      fin + (t & 1) * 64, fin + ((t + 1) & 1) * 64,
                                      xT, outTok, t);
  }
  k_hout<<<256, 256, 0, stream>>>(hT, outH);
}

// Round 4
// 5109.217 us; speedup vs baseline: 2.7850x; 2.7850x over previous
//
#include <hip/hip_runtime.h>
#include <math.h>

// Problem constants
#define BB   64
#define HENC 512
#define EE   512
#define HH   1024
#define VV   32000
#define TT   64
#define G3   3072   // 3*H
#define SOS_TOK 1
#define EOS_TOK 2
#define KSEG 128
#define NP2  4000   // argmax partial entries (2000 waves * top-2)

typedef __attribute__((ext_vector_type(8))) short short8;
typedef __attribute__((ext_vector_type(8))) unsigned short ushort8;
typedef __attribute__((ext_vector_type(4))) float f32x4;
typedef unsigned short ushort;
typedef unsigned int uint;

// Workspace layout (float offsets).
// NOTE (R3 bug, fixed R4): hA is 64*1024 bf16 = 65536 ushorts = 32768 FLOATS.
// R3 reserved 16384 floats -> k_combine overran 64KB into Wb, corrupting
// packed vocab rows 0..63 -> garbage argmax. Offsets below give hA its full size.
#define OFF_FLATT 0u          // 65536
#define OFF_XT    65536u      // 32768
#define OFF_HT    98304u      // 65536   hT[g][b]
#define OFF_GC    163840u     // 196608  gc[b][n] = b_ih + context@Wih_ctx
#define OFF_P     360448u     // 8*64*3072 = 1572864 gate partials
#define OFF_PH    1933312u    // 8*65536 = 524288  h0 partials
#define OFF_PMAX  2457600u    // 256000
#define OFF_PIDX  2713600u    // 256000
#define OFF_FIN   2969600u    // 128 (double-buffered by t parity)
#define OFF_HA    2969728u    // 32768 floats (64x1024 bf16 A-frag packed h)
#define OFF_WB    3002496u    // 16384000 floats (32000x1024 bf16 B-frag W) [optional]
#define OFF_END   19386496u
#define NEED_BYTES ((size_t)OFF_END * 4u)   // 77,545,984

__device__ __forceinline__ ushort f2bf(float x) {
  uint u = __float_as_uint(x);
  u = u + 0x7fffu + ((u >> 16) & 1u);   // RNE
  return (ushort)(u >> 16);
}

// ---------------------------------------------------------------------------
__global__ __launch_bounds__(256) void k_setup(const float* __restrict__ enc,
                                               const float* __restrict__ emb,
                                               float* __restrict__ flatT,
                                               float* __restrict__ xT,
                                               int* __restrict__ fin0) {
  int idx = blockIdx.x * 256 + threadIdx.x;   // 65536
  int j = idx >> 6, b = idx & 63;
  float v = (j < 512) ? enc[b * 512 + j] : enc[32768 + b * 512 + (j - 512)];
  flatT[j * 64 + b] = v;
  if (j < 512) xT[j * 64 + b] = emb[SOS_TOK * EE + j];
  if (idx < 64) fin0[idx] = 0;
}

// ---------------------------------------------------------------------------
// Optional: pack out_w fp32 -> bf16 in B-fragment stream order.
// chunk c = (nt*32 + kc)*64 + lane ; element j: n = nt*16+(lane&15), k = kc*32+(lane>>4)*8+j
__global__ __launch_bounds__(256) void k_packWb(const float* __restrict__ W,
                                                ushort* __restrict__ Wb) {
  int t = blockIdx.x * 256 + threadIdx.x;     // 4,096,000 chunks
  int l = t & 63, kc = (t >> 6) & 31, nt = t >> 11;
  int n = nt * 16 + (l & 15);
  int k = kc * 32 + ((l >> 4) << 3);
  const float* src = W + (size_t)n * 1024 + k;
  ushort8 r;
  #pragma unroll
  for (int j = 0; j < 8; ++j) r[j] = f2bf(src[j]);
  *(ushort8*)(Wb + (size_t)t * 8) = r;
}

// ---------------------------------------------------------------------------
// Generic fp32 skinny GEMM partial (setup only).
__global__ __launch_bounds__(256) void k_gemm(const float* __restrict__ AT,
                                              const float* __restrict__ W,
                                              int ldw, int wofs,
                                              float* __restrict__ C, int N) {
  __shared__ float Ws[KSEG][65];
  int tid = threadIdx.x;
  int n0 = blockIdx.x * 64;
  int k0 = blockIdx.y * KSEG;

  #pragma unroll
  for (int r = 0; r < 8; ++r) {
    int f4 = tid + 256 * r;
    int n = f4 >> 5, kq = f4 & 31;
    float4 w4 = *(const float4*)&W[(size_t)(n0 + n) * ldw + wofs + k0 + 4 * kq];
    Ws[4 * kq + 0][n] = w4.x;
    Ws[4 * kq + 1][n] = w4.y;
    Ws[4 * kq + 2][n] = w4.z;
    Ws[4 * kq + 3][n] = w4.w;
  }
  __syncthreads();

  int wv = __builtin_amdgcn_readfirstlane(tid >> 6);
  int lane = tid & 63;
  int mb = wv * 16;

  float acc[16];
  #pragma unroll
  for (int i = 0; i < 16; ++i) acc[i] = 0.f;

  #pragma unroll 4
  for (int kk = 0; kk < KSEG; ++kk) {
    float w = Ws[kk][lane];
    const float* a = &AT[(size_t)(k0 + kk) * 64 + mb];
    float av[16];
    *(float4*)&av[0]  = *(const float4*)(a + 0);
    *(float4*)&av[4]  = *(const float4*)(a + 4);
    *(float4*)&av[8]  = *(const float4*)(a + 8);
    *(float4*)&av[12] = *(const float4*)(a + 12);
    #pragma unroll
    for (int i = 0; i < 16; ++i) acc[i] += av[i] * w;
  }

  float* dst = C + ((size_t)blockIdx.y * 64 + mb) * N + n0 + lane;
  #pragma unroll
  for (int i = 0; i < 16; ++i) dst[(size_t)i * N] = acc[i];
}

// ---------------------------------------------------------------------------
// Fused per-step gates: by<4 -> gi seg (xT @ W_ih[:, :512]); by in 4..7 -> gh
// (hT @ W_hh) covering 256 K each (two 128 stages). P slot = by (8 slots).
__global__ __launch_bounds__(256) void k_gates(const float* __restrict__ xT,
                                               const float* __restrict__ hT,
                                               const float* __restrict__ Wih,
                                               const float* __restrict__ Whh,
                                               float* __restrict__ P) {
  __shared__ float Ws[KSEG][65];
  int tid = threadIdx.x;
  int n0 = blockIdx.x * 64;
  int by = blockIdx.y;
  bool gi = (by < 4);
  const float* AT = gi ? xT : hT;
  const float* W  = gi ? Wih : Whh;
  int ldw = gi ? 1536 : 1024;
  int nsegs = gi ? 1 : 2;
  int k0base = gi ? by * KSEG : (by - 4) * 256;

  int wv = __builtin_amdgcn_readfirstlane(tid >> 6);
  int lane = tid & 63;
  int mb = wv * 16;

  float acc[16];
  #pragma unroll
  for (int i = 0; i < 16; ++i) acc[i] = 0.f;

  for (int s = 0; s < nsegs; ++s) {
    int k0 = k0base + s * KSEG;
    if (s) __syncthreads();
    #pragma unroll
    for (int r = 0; r < 8; ++r) {
      int f4 = tid + 256 * r;
      int n = f4 >> 5, kq = f4 & 31;
      float4 w4 = *(const float4*)&W[(size_t)(n0 + n) * ldw + k0 + 4 * kq];
      Ws[4 * kq + 0][n] = w4.x;
      Ws[4 * kq + 1][n] = w4.y;
      Ws[4 * kq + 2][n] = w4.z;
      Ws[4 * kq + 3][n] = w4.w;
    }
    __syncthreads();
    #pragma unroll 4
    for (int kk = 0; kk < KSEG; ++kk) {
      float w = Ws[kk][lane];
      const float* a = &AT[(size_t)(k0 + kk) * 64 + mb];
      float av[16];
      *(float4*)&av[0]  = *(const float4*)(a + 0);
      *(float4*)&av[4]  = *(const float4*)(a + 4);
      *(float4*)&av[8]  = *(const float4*)(a + 8);
      *(float4*)&av[12] = *(const float4*)(a + 12);
      #pragma unroll
      for (int i = 0; i < 16; ++i) acc[i] += av[i] * w;
    }
  }

  float* dst = P + ((size_t)by * 64 + mb) * G3 + n0 + lane;
  #pragma unroll
  for (int i = 0; i < 16; ++i) dst[(size_t)i * G3] = acc[i];
}

// ---------------------------------------------------------------------------
__global__ __launch_bounds__(256) void k_reduce_gc(const float* __restrict__ P,
                                                   const float* __restrict__ b_ih,
                                                   float* __restrict__ gc) {
  int idx = blockIdx.x * 256 + threadIdx.x;  // 196608
  int n = idx % G3;
  float s = b_ih[n];
  #pragma unroll
  for (int p = 0; p < 8; ++p) s += P[(size_t)p * (64 * G3) + idx];
  gc[idx] = s;
}

// Pack one h element (m=b, k=g) into bf16 A-frag layout.
__device__ __forceinline__ void packH1(float v, int b, int g, ushort* hA) {
  int kc = g >> 5, q = (g >> 3) & 3, j = g & 7;
  int lane = (q << 4) | (b & 15), mt = b >> 4;
  size_t fi = ((size_t)((mt * 32 + kc) * 64 + lane)) * 8 + j;
  hA[fi] = f2bf(v);
}

__global__ __launch_bounds__(256) void k_reduce_h0(const float* __restrict__ Ph,
                                                   const float* __restrict__ Wh_b,
                                                   float* __restrict__ hT,
                                                   ushort* __restrict__ hA) {
  int idx = blockIdx.x * 256 + threadIdx.x;  // 65536
  int b = idx >> 10, g = idx & 1023;
  float s = Wh_b[g];
  #pragma unroll
  for (int p = 0; p < 8; ++p) s += Ph[(size_t)p * 65536 + idx];
  hT[g * 64 + b] = s;
  packH1(s, b, g, hA);
}

// ---------------------------------------------------------------------------
// GRU combine; emits fp32 hT and bf16 A-frag hA. P slots 0..3 gi, 4..7 gh.
__global__ __launch_bounds__(256) void k_combine(const float* __restrict__ P,
                                                 const float* __restrict__ gc,
                                                 const float* __restrict__ b_hh,
                                                 float* __restrict__ hT,
                                                 ushort* __restrict__ hA) {
  int b = blockIdx.x;
  #pragma unroll
  for (int r = 0; r < 4; ++r) {
    int g = threadIdx.x + 256 * r;
    float ir = gc[b * G3 + g];
    float iz = gc[b * G3 + 1024 + g];
    float in_ = gc[b * G3 + 2048 + g];
    float hr = b_hh[g], hz = b_hh[1024 + g], hn = b_hh[2048 + g];
    #pragma unroll
    for (int p = 0; p < 4; ++p) {
      const float* row = P + ((size_t)p * 64 + b) * G3;
      ir += row[g]; iz += row[1024 + g]; in_ += row[2048 + g];
    }
    #pragma unroll
    for (int p = 4; p < 8; ++p) {
      const float* row = P + ((size_t)p * 64 + b) * G3;
      hr += row[g]; hz += row[1024 + g]; hn += row[2048 + g];
    }
    float rr = 1.f / (1.f + expf(-(ir + hr)));
    float zz = 1.f / (1.f + expf(-(iz + hz)));
    float nn = tanhf(in_ + rr * hn);
    float hold = hT[g * 64 + b];
    float hnew = (1.f - zz) * nn + zz * hold;
    hT[g * 64 + b] = hnew;
    packH1(hnew, b, g, hA);
  }
}

// ---------------------------------------------------------------------------
__device__ __forceinline__ short8 cvt8(const float* p) {
  float4 x = *(const float4*)p;
  float4 y = *(const float4*)(p + 4);
  short8 r;
  r[0] = (short)f2bf(x.x); r[1] = (short)f2bf(x.y);
  r[2] = (short)f2bf(x.z); r[3] = (short)f2bf(x.w);
  r[4] = (short)f2bf(y.x); r[5] = (short)f2bf(y.y);
  r[6] = (short)f2bf(y.z); r[7] = (short)f2bf(y.w);
  return r;
}

// MFMA logits, single bf16 pass, fused per-wave top-2 partials.
// 500 blocks x 256 thr; wave = 1 n-tile (16 vocab) x 4 m-tiles; depth-4 ring.
template <bool PACKED>
__global__ __launch_bounds__(256) void k_logits(const ushort* __restrict__ Wb,
                                                const float* __restrict__ Wf,
                                                const ushort* __restrict__ hA,
                                                const float* __restrict__ bo,
                                                float* __restrict__ pmax,
                                                int* __restrict__ pidx) {
  int tid = threadIdx.x, wv = tid >> 6, lane = tid & 63;
  int nt = blockIdx.x * 4 + wv;           // 0..1999
  int nl = lane & 15, q = lane >> 4;

  const short8* Bp = (const short8*)Wb + ((size_t)nt * 2048 + lane);
  const float*  Bf = Wf + (size_t)(nt * 16 + nl) * 1024 + (q << 3);
  const short8* Ap = (const short8*)hA + lane;

  f32x4 acc[4];
  #pragma unroll
  for (int m = 0; m < 4; ++m) acc[m] = (f32x4){0.f, 0.f, 0.f, 0.f};

  short8 bR[4], aR[4][4];
  #pragma unroll
  for (int d = 0; d < 4; ++d) {
    bR[d] = PACKED ? Bp[d * 64] : cvt8(Bf + d * 32);
    #pragma unroll
    for (int m = 0; m < 4; ++m) aR[d][m] = Ap[(m * 32 + d) * 64];
  }

  #pragma unroll
  for (int kc = 0; kc < 32; ++kc) {
    const int sl = kc & 3;
    #pragma unroll
    for (int m = 0; m < 4; ++m)
      acc[m] = __builtin_amdgcn_mfma_f32_16x16x32_bf16(aR[sl][m], bR[sl], acc[m], 0, 0, 0);
    if (kc < 28) {
      bR[sl] = PACKED ? Bp[(kc + 4) * 64] : cvt8(Bf + (kc + 4) * 32);
      #pragma unroll
      for (int m = 0; m < 4; ++m) aR[sl][m] = Ap[(m * 32 + kc + 4) * 64];
    }
  }

  // Epilogue: bias + per-(row) top-2 over this wave's 16 columns.
  float bias = bo[nt * 16 + nl];
  int myn = nt * 16 + nl;
  #pragma unroll
  for (int mt = 0; mt < 4; ++mt) {
    #pragma unroll
    for (int r = 0; r < 4; ++r) {
      float v1 = acc[mt][r] + bias; int i1 = myn;
      float v2 = -3.402823466e38f;  int i2 = 0x7fffffff;
      #pragma unroll
      for (int s = 1; s < 16; s <<= 1) {
        float ov1 = __shfl_xor(v1, s, 64); int oi1 = __shfl_xor(i1, s, 64);
        float ov2 = __shfl_xor(v2, s, 64); int oi2 = __shfl_xor(i2, s, 64);
        bool take = (ov1 > v1) || (ov1 == v1 && oi1 < i1);
        float n1v = take ? ov1 : v1; int n1i = take ? oi1 : i1;
        float cav = take ? v1 : ov1; int cai = take ? i1 : oi1;
        float cbv = take ? ov2 : v2; int cbi = take ? oi2 : i2;
        bool bb = (cbv > cav) || (cbv == cav && cbi < cai);
        v1 = n1v; i1 = n1i;
        v2 = bb ? cbv : cav; i2 = bb ? cbi : cai;
      }
      if (nl == 0) {
        int m = mt * 16 + q * 4 + r;
        pmax[(nt * 2 + 0) * 64 + m] = v1;
        pidx[(nt * 2 + 0) * 64 + m] = i1;
        pmax[(nt * 2 + 1) * 64 + m] = v2;
        pidx[(nt * 2 + 1) * 64 + m] = i2;
      }
    }
  }
}

// ---------------------------------------------------------------------------
// Per-batch finisher: approx top-4 candidates -> fp64 rescore -> token, fin,
// embedding gather. One block per batch.
__global__ __launch_bounds__(256) void k_finish(const float* __restrict__ pmax,
                                                const int* __restrict__ pidx,
                                                const float* __restrict__ hT,
                                                const float* __restrict__ Wf,
                                                const float* __restrict__ bo,
                                                const float* __restrict__ emb,
                                                const int* __restrict__ fin_old,
                                                int* __restrict__ fin_new,
                                                float* __restrict__ xT,
                                                float* __restrict__ tok_out, int t) {
  __shared__ float bv[256];
  __shared__ int   bi[256];
  __shared__ int    sch[4];
  __shared__ double ssc[4];
  __shared__ int    sinp;
  int b = blockIdx.x, tid = threadIdx.x;

  float cv[16]; int ci[16];
  #pragma unroll
  for (int j = 0; j < 16; ++j) {
    int p = tid + j * 256;
    if (p < NP2) { cv[j] = pmax[p * 64 + b]; ci[j] = pidx[p * 64 + b]; }
    else         { cv[j] = -3.402823466e38f; ci[j] = 0x7fffffff; }
  }

  int ch0 = -1, ch1 = -1, ch2 = -1;
  for (int r = 0; r < 4; ++r) {
    float v = -3.402823466e38f; int id = 0x7fffffff;
    #pragma unroll
    for (int j = 0; j < 16; ++j) {
      bool ex = (ci[j] == ch0) | (ci[j] == ch1) | (ci[j] == ch2);
      if (!ex && (cv[j] > v || (cv[j] == v && ci[j] < id))) { v = cv[j]; id = ci[j]; }
    }
    bv[tid] = v; bi[tid] = id;
    __syncthreads();
    for (int s = 128; s > 0; s >>= 1) {
      if (tid < s) {
        float ov = bv[tid + s]; int oi = bi[tid + s];
        if (ov > bv[tid] || (ov == bv[tid] && oi < bi[tid])) { bv[tid] = ov; bi[tid] = oi; }
      }
      __syncthreads();
    }
    if (tid == 0) sch[r] = bi[0];
    __syncthreads();
    int c = sch[r];
    if (r == 0) ch0 = c; else if (r == 1) ch1 = c; else if (r == 2) ch2 = c;
  }

  // fp64 rescore: wave c handles candidate c.
  int c = tid >> 6, ln = tid & 63;
  int cid = sch[c];
  double s = 0.0;
  #pragma unroll 4
  for (int k = ln; k < 1024; k += 64)
    s += (double)hT[k * 64 + b] * (double)Wf[(size_t)cid * 1024 + k];
  #pragma unroll
  for (int sh = 1; sh < 64; sh <<= 1) s += __shfl_xor(s, sh, 64);
  if (ln == 0) ssc[c] = s + (double)bo[cid];
  __syncthreads();

  if (tid == 0) {
    double bs = ssc[0]; int bid = sch[0];
    #pragma unroll
    for (int j = 1; j < 4; ++j)
      if (ssc[j] > bs || (ssc[j] == bs && sch[j] < bid)) { bs = ssc[j]; bid = sch[j]; }
    int tok = bid;
    int f = fin_old[b] | (tok == EOS_TOK ? 1 : 0);
    tok_out[b * TT + t] = (float)tok;
    fin_new[b] = f;
    sinp = f ? EOS_TOK : tok;
  }
  __syncthreads();
  int inp = sinp;
  xT[tid * 64 + b]         = emb[(size_t)inp * EE + tid];
  xT[(tid + 256) * 64 + b] = emb[(size_t)inp * EE + tid + 256];
}

// ---------------------------------------------------------------------------
__global__ __launch_bounds__(256) void k_hout(const float* __restrict__ hT,
                                              float* __restrict__ outH) {
  int idx = blockIdx.x * 256 + threadIdx.x;  // 65536
  int b = idx >> 10, g = idx & 1023;
  outH[idx] = hT[g * 64 + b];
}

// ---------------------------------------------------------------------------
extern "C" void kernel_launch(void* const* d_in, const int* in_sizes, int n_in,
                              void* d_out, int out_size, void* d_ws, size_t ws_size,
                              hipStream_t stream) {
  const float* enc   = (const float*)d_in[0];
  const float* emb   = (const float*)d_in[1];
  const float* Wh_w  = (const float*)d_in[2];
  const float* Wh_b  = (const float*)d_in[3];
  const float* W_ih  = (const float*)d_in[4];
  const float* W_hh  = (const float*)d_in[5];
  const float* b_ih  = (const float*)d_in[6];
  const float* b_hh  = (const float*)d_in[7];
  const float* out_w = (const float*)d_in[8];
  const float* out_b = (const float*)d_in[9];

  float* ws    = (float*)d_ws;
  float* flatT = ws + OFF_FLATT;
  float* xT    = ws + OFF_XT;
  float* hT    = ws + OFF_HT;
  float* gc    = ws + OFF_GC;
  float* P     = ws + OFF_P;
  float* Ph    = ws + OFF_PH;
  float* pmax  = ws + OFF_PMAX;
  int*   pidx  = (int*)(ws + OFF_PIDX);
  int*   fin   = (int*)(ws + OFF_FIN);
  ushort* hA   = (ushort*)(ws + OFF_HA);
  ushort* Wb   = (ushort*)(ws + OFF_WB);

  float* outTok = (float*)d_out;
  float* outH   = (float*)d_out + BB * TT;

  const bool packed = (ws_size >= NEED_BYTES);

  // Setup
  k_setup<<<256, 256, 0, stream>>>(enc, emb, flatT, xT, fin);
  if (packed) k_packWb<<<16000, 256, 0, stream>>>(out_w, Wb);
  // gc = b_ih + context @ W_ih[:, 512:1536]^T
  k_gemm<<<dim3(48, 8), 256, 0, stream>>>(flatT, W_ih, 1536, 512, P, G3);
  k_reduce_gc<<<768, 256, 0, stream>>>(P, b_ih, gc);
  // h0 = flat @ Wh_w^T + Wh_b
  k_gemm<<<dim3(16, 8), 256, 0, stream>>>(flatT, Wh_w, 1024, 0, Ph, HH);
  k_reduce_h0<<<256, 256, 0, stream>>>(Ph, Wh_b, hT, hA);

  for (int t = 0; t < TT; ++t) {
    k_gates<<<dim3(48, 8), 256, 0, stream>>>(xT, hT, W_ih, W_hh, P);
    k_combine<<<64, 256, 0, stream>>>(P, gc, b_hh, hT, hA);
    if (packed)
      k_logits<true><<<500, 256, 0, stream>>>(Wb, out_w, hA, out_b, pmax, pidx);
    else
      k_logits<false><<<500, 256, 0, stream>>>(Wb, out_w, hA, out_b, pmax, pidx);
    k_finish<<<64, 256, 0, stream>>>(pmax, pidx, hT, out_w, out_b, emb,
                                     fin + (t & 1) * 64, fin + ((t + 1) & 1) * 64,
                                     xT, outTok, t);
  }
  k_hout<<<256, 256, 0, stream>>>(hT, outH);
}